// Round 18
// baseline (1655.125 us; speedup 1.0000x reference)
//
#include <hip/hip_runtime.h>

#define BB 32
#define TT 256
#define HH 512
#define ALD 1032   // A_lds padded row stride in elements (1024 + 8)
#define ZLD 68     // z_lds padded row stride in floats (64 + 4)
#define FLGSTRIDE 32   // u32s per flag line (128 B)
#define GRIDN 512

typedef float    f32x4 __attribute__((ext_vector_type(4)));
typedef float    f32x2 __attribute__((ext_vector_type(2)));
typedef int      i32x4 __attribute__((ext_vector_type(4)));
typedef _Float16 f16x8 __attribute__((ext_vector_type(8)));
typedef unsigned long long u64;

__device__ __forceinline__ unsigned short f2h(float f) {
  union { _Float16 h; unsigned short u; } v; v.h = (_Float16)f; return v.u;
}
__device__ __forceinline__ int pkh2(float a, float b) {
  return (int)((unsigned int)f2h(a) | ((unsigned int)f2h(b) << 16));
}
__device__ __forceinline__ float sigm(float x) { return 1.f / (1.f + __expf(-x)); }
__device__ __forceinline__ float tanh_(float x) {
  float ax = fabsf(x);
  float e = __expf(-2.f * ax);
  float r = (1.f - e) / (1.f + e);
  return copysignf(r, x);
}
// fabric-coherent pipelined 16B load (sc1: bypasses L1+L2, device scope)
__device__ __forceinline__ void ld_coh16(i32x4& dst, const void* a) {
  asm volatile("global_load_dwordx4 %0, %1, off sc1" : "=v"(dst) : "v"(a) : "memory");
}
// XCD-local pipelined 16B load (sc0: bypasses L1, reads own-XCD shared L2)
__device__ __forceinline__ void ld_l2_16(i32x4& dst, const void* a) {
  asm volatile("global_load_dwordx4 %0, %1, off sc0" : "=v"(dst) : "v"(a) : "memory");
}
// XCD-local 4B load (sc0)
__device__ __forceinline__ unsigned int ld_l2_4(const void* a) {
  unsigned int v;
  asm volatile("global_load_dword %0, %1, off sc0" : "=v"(v) : "v"(a) : "memory");
  asm volatile("s_waitcnt vmcnt(0)" ::: "memory");
  return v;
}
// XCD-local stores (plain: write-through L1 into own-XCD L2)
__device__ __forceinline__ void st_l2_8(void* a, u64 v) {
  asm volatile("global_store_dwordx2 %0, %1, off" :: "v"(a), "v"(v) : "memory");
}
__device__ __forceinline__ void st_l2_4(void* a, unsigned int v) {
  asm volatile("global_store_dword %0, %1, off" :: "v"(a), "v"(v) : "memory");
}

__global__ void zero_ws_kernel(unsigned int* p, int nwords) {
  int i = blockIdx.x * 256 + threadIdx.x;
  if (i < nwords) p[i] = 0u;
}

// 512 blocks launched; 64 claim roles (L0 on home XCD, L1 on home+1), rest exit.
// Per-layer sync via local-L2 flag lines (tiny spin traffic) + one bulk sc0 load;
// inline tags verified once; r17 retry/sc1-fallback kept as correctness backstop.
__global__ __launch_bounds__(256, 1) void lstm_enc_kernel(
    const int* __restrict__ tokens,
    const int* __restrict__ lengths,
    const float* __restrict__ emb,     // [V][512] fp32
    const float* __restrict__ Wx,      // [2][512][2048] fp32
    const float* __restrict__ Wh,      // [2][512][2048] fp32
    const float* __restrict__ bias,    // [2][2048] fp32
    float* __restrict__ out,           // y ++ c ++ h fp32
    unsigned short* __restrict__ ws_y, // [32][256][512] f16 bits
    u64* __restrict__ htagL,           // [2][2][32][256] tagged h (XCD-local copy)
    u64* __restrict__ htagG,           // [2][2][32][256] tagged h (fabric copy)
    unsigned int* __restrict__ flags,  // [32] L0 fabric flags, 128B-strided
    unsigned int* __restrict__ flagsL, // [2][32] local-L2 flags, 128B-strided
    unsigned int* __restrict__ ctl)    // [0]=home|0x100, [32]=ctrA, [64]=ctrB, [96]=claimed
{
  const int tid = threadIdx.x;

  // ---- role claim: L0 roles on home XCD, L1 on home+1; overflow after capped spin
  __shared__ int sRole;
  if (tid == 0) {
    unsigned int xcc;
    asm volatile("s_getreg_b32 %0, hwreg(HW_REG_XCC_ID)" : "=s"(xcc));
    xcc &= 7u;
    if (blockIdx.x == 0) {
      __hip_atomic_store(&ctl[0], 0x100u | xcc, __ATOMIC_RELAXED, __HIP_MEMORY_SCOPE_AGENT);
    }
    unsigned int hw;
    while ((((hw = __hip_atomic_load(&ctl[0], __ATOMIC_RELAXED, __HIP_MEMORY_SCOPE_AGENT))) & 0x100u) == 0u) {
      __builtin_amdgcn_s_sleep(1);
    }
    const unsigned int home0 = hw & 7u, home1 = (home0 + 1u) & 7u;
    int role = -1;
    if (xcc == home0) {
      unsigned int i = __hip_atomic_fetch_add(&ctl[32], 1u, __ATOMIC_RELAXED, __HIP_MEMORY_SCOPE_AGENT);
      if (i < 32u) role = (int)i;
    } else if (xcc == home1) {
      unsigned int i = __hip_atomic_fetch_add(&ctl[64], 1u, __ATOMIC_RELAXED, __HIP_MEMORY_SCOPE_AGENT);
      if (i < 32u) role = 32 + (int)i;
    }
    if (role < 0) {
      unsigned int cl = 0; int spins = 0;
      while ((cl = __hip_atomic_load(&ctl[96], __ATOMIC_RELAXED, __HIP_MEMORY_SCOPE_AGENT)) < 64u
             && spins < 20000) { __builtin_amdgcn_s_sleep(2); ++spins; }
      if (cl < 64u) {
        unsigned int i = __hip_atomic_fetch_add(&ctl[32], 1u, __ATOMIC_RELAXED, __HIP_MEMORY_SCOPE_AGENT);
        if (i < 32u) role = (int)i;
        else {
          unsigned int j = __hip_atomic_fetch_add(&ctl[64], 1u, __ATOMIC_RELAXED, __HIP_MEMORY_SCOPE_AGENT);
          if (j < 32u) role = 32 + (int)j;
        }
      }
    }
    if (role >= 0)
      __hip_atomic_fetch_add(&ctl[96], 1u, __ATOMIC_RELAXED, __HIP_MEMORY_SCOPE_AGENT);
    sRole = role;
  }
  __syncthreads();
  const int role = sRole;
  if (role < 0) return;
  const int layer = role >> 5;
  const int lblk  = role & 31;
  const int wave  = tid >> 6;
  const int lane  = tid & 63;

  __shared__ unsigned short Alds[32 * ALD];
  __shared__ float zlds[32 * ZLD];

  // ---- preload stacked-weight B fragments (K = 1024, N = 16 per wave)
  const int nloc  = lane & 15;
  const int gcol  = wave * HH + lblk * 16 + nloc;
  const int krow0 = (lane >> 4) * 8;
  const float* WxL = Wx + (size_t)layer * HH * 2048;
  const float* WhL = Wh + (size_t)layer * HH * 2048;
  f16x8 breg[32];
#pragma unroll
  for (int s = 0; s < 32; ++s) {
    const float* base = (s < 16)
        ? (WxL + (size_t)(s * 32 + krow0) * 2048 + gcol)
        : (WhL + (size_t)((s - 16) * 32 + krow0) * 2048 + gcol);
    f16x8 v;
    v[0] = (_Float16)base[0 * 2048];
    v[1] = (_Float16)base[1 * 2048];
    v[2] = (_Float16)base[2 * 2048];
    v[3] = (_Float16)base[3 * 2048];
    v[4] = (_Float16)base[4 * 2048];
    v[5] = (_Float16)base[5 * 2048];
    v[6] = (_Float16)base[6 * 2048];
    v[7] = (_Float16)base[7 * 2048];
    breg[s] = v;
  }

  // ---- per-thread elementwise state: one batch, two adjacent units
  const int jj  = tid & 7;
  const int eb  = tid >> 3;
  const int u0  = lblk * 16 + 2 * jj;
  const int len = lengths[eb];
  const float bI0 = bias[layer * 2048 +         u0], bI1 = bias[layer * 2048 +         u0 + 1];
  const float bF0 = bias[layer * 2048 +  512 +  u0], bF1 = bias[layer * 2048 +  512 +  u0 + 1];
  const float bG0 = bias[layer * 2048 + 1024 +  u0], bG1 = bias[layer * 2048 + 1024 +  u0 + 1];
  const float bO0 = bias[layer * 2048 + 1536 +  u0], bO1 = bias[layer * 2048 + 1536 +  u0 + 1];
  float cA = 0.f, hA = 0.f, cB = 0.f, hB = 0.f;

  u64* hlayL = htagL + (size_t)layer * 2 * BB * 256;
  u64* hlayG = htagG + (size_t)layer * 2 * BB * 256;
  unsigned int* pollL0  = flags + (size_t)(tid & 31) * FLGSTRIDE;
  unsigned int* pollLoc = flagsL + (size_t)(layer * 32 + (tid & 31)) * FLGSTRIDE;
  unsigned int* myFlagL = flagsL + (size_t)(layer * 32 + lblk) * FLGSTRIDE;
  bool useG = false;   // sticky fallback to fabric copy

  // ---- prologue: layer 0 stages x(0) into LDS x-half
  if (layer == 0) {
#pragma unroll
    for (int i = 0; i < 8; ++i) {
      int u   = tid + i * 256;
      int row = u >> 6;
      int ce  = (u & 63) * 8;
      int tok = tokens[row * TT + 0];
      const float* src = emb + (size_t)tok * HH + ce;
      f32x4 lo = *(const f32x4*)src;
      f32x4 hi = *(const f32x4*)(src + 4);
      i32x4 w;
      w[0] = pkh2(lo[0], lo[1]); w[1] = pkh2(lo[2], lo[3]);
      w[2] = pkh2(hi[0], hi[1]); w[3] = pkh2(hi[2], hi[3]);
      *(i32x4*)(&Alds[row * ALD + ce]) = w;
    }
  }

  for (int it = 0;; ++it) {
    const int t = (layer == 0) ? it : (it - 1);
    const bool active = (t >= 0) && (t < TT);

    if (layer == 1 && active) {
      const unsigned int tgt = (unsigned int)(t + 1);
      if (tid < 32) {
        while (__hip_atomic_load(pollL0, __ATOMIC_RELAXED, __HIP_MEMORY_SCOPE_AGENT) < tgt) {
          __builtin_amdgcn_s_sleep(1);
        }
      }
      __syncthreads();
      i32x4 yv[8];
      int yrow[8], yco[8];
#pragma unroll
      for (int k = 0; k < 8; ++k) {
        int g = tid + k * 256;
        yrow[k] = g >> 6;
        yco[k]  = (g & 63) * 8;
        ld_coh16(yv[k], ws_y + ((size_t)yrow[k] * TT + t) * HH + yco[k]);
      }
      asm volatile("s_waitcnt vmcnt(0)" ::: "memory");
      __builtin_amdgcn_sched_barrier(0);
#pragma unroll
      for (int k = 0; k < 8; ++k) {
        *(i32x4*)(&Alds[yrow[k] * ALD + yco[k]]) = yv[k];
      }
    }

    if (active) {
      // ---- local flag barrier: peers finished step t-1 (flag >= t); 128B/round spin
      const unsigned int tgtF = (unsigned int)t;
      if (tid < 32) {
        while (ld_l2_4(pollLoc) < tgtF) __builtin_amdgcn_s_sleep(1);
      }
      __syncthreads();
      // ---- ONE bulk sc0 load + tag verify (backstop: r17 retry w/ sc1 sticky)
      const u64* srcL = hlayL + (size_t)(t & 1) * BB * 256;
      const u64* srcG = hlayG + (size_t)(t & 1) * BB * 256;
      const unsigned int exp = (unsigned int)t;
      i32x4 hv[16];
#pragma unroll
      for (int k = 0; k < 16; ++k) ld_l2_16(hv[k], srcL + 2 * (tid + k * 256));
      asm volatile("s_waitcnt vmcnt(0)" ::: "memory");
      __builtin_amdgcn_sched_barrier(0);
      bool ok = true;
#pragma unroll
      for (int k = 0; k < 16; ++k) {
        if ((unsigned int)hv[k][1] != exp) ok = false;
        if ((unsigned int)hv[k][3] != exp) ok = false;
      }
      int rounds = 0;
      while (!ok) {
        if (useG) {
#pragma unroll
          for (int k = 0; k < 16; ++k) ld_coh16(hv[k], srcG + 2 * (tid + k * 256));
        } else {
#pragma unroll
          for (int k = 0; k < 16; ++k) ld_l2_16(hv[k], srcL + 2 * (tid + k * 256));
        }
        asm volatile("s_waitcnt vmcnt(0)" ::: "memory");
        __builtin_amdgcn_sched_barrier(0);
        ok = true;
#pragma unroll
        for (int k = 0; k < 16; ++k) {
          if ((unsigned int)hv[k][1] != exp) ok = false;
          if ((unsigned int)hv[k][3] != exp) ok = false;
        }
        if (!ok && ++rounds > 48) useG = true;
      }
#pragma unroll
      for (int k = 0; k < 16; ++k) {
        int g   = tid + k * 256;
        int row = g >> 7;
        int e   = 4 * (g & 127);
        u64 d = (u64)(unsigned int)hv[k][0] | ((u64)(unsigned int)hv[k][2] << 32);
        *(u64*)(&Alds[row * ALD + 512 + e]) = d;
      }
    }
    __syncthreads();

    if (active) {
      // ---- 4 shortened MFMA chains (2x16 deep per acc) over K=1024
      f32x4 acc0a = {0.f,0.f,0.f,0.f}, acc0b = {0.f,0.f,0.f,0.f};
      f32x4 acc1a = {0.f,0.f,0.f,0.f}, acc1b = {0.f,0.f,0.f,0.f};
      const _Float16* a0p = (const _Float16*)&Alds[nloc * ALD + krow0];
      const _Float16* a1p = a0p + 16 * ALD;
#pragma unroll
      for (int s = 0; s < 16; ++s) {
        f16x8 a0 = *(const f16x8*)(a0p + s * 32);
        f16x8 a1 = *(const f16x8*)(a1p + s * 32);
        acc0a = __builtin_amdgcn_mfma_f32_16x16x32_f16(a0, breg[s], acc0a, 0, 0, 0);
        acc1a = __builtin_amdgcn_mfma_f32_16x16x32_f16(a1, breg[s], acc1a, 0, 0, 0);
      }
#pragma unroll
      for (int s = 16; s < 32; ++s) {
        f16x8 a0 = *(const f16x8*)(a0p + s * 32);
        f16x8 a1 = *(const f16x8*)(a1p + s * 32);
        acc0b = __builtin_amdgcn_mfma_f32_16x16x32_f16(a0, breg[s], acc0b, 0, 0, 0);
        acc1b = __builtin_amdgcn_mfma_f32_16x16x32_f16(a1, breg[s], acc1b, 0, 0, 0);
      }
      const int zc = wave * 16 + nloc;
      const int zr = (lane >> 4) * 4;
#pragma unroll
      for (int r = 0; r < 4; ++r) {
        zlds[(zr + r) * ZLD + zc]        = acc0a[r] + acc0b[r];
        zlds[(16 + zr + r) * ZLD + zc]   = acc1a[r] + acc1b[r];
      }
    }
    __syncthreads();

    if (active) {
      float zi0 = zlds[eb * ZLD +      2 * jj] + bI0, zi1 = zlds[eb * ZLD +      2 * jj + 1] + bI1;
      float zf0 = zlds[eb * ZLD + 16 + 2 * jj] + bF0, zf1 = zlds[eb * ZLD + 16 + 2 * jj + 1] + bF1;
      float zg0 = zlds[eb * ZLD + 32 + 2 * jj] + bG0, zg1 = zlds[eb * ZLD + 32 + 2 * jj + 1] + bG1;
      float zo0 = zlds[eb * ZLD + 48 + 2 * jj] + bO0, zo1 = zlds[eb * ZLD + 48 + 2 * jj + 1] + bO1;
      float ncA = sigm(zf0) * cA + sigm(zi0) * tanh_(zg0);
      float nhA = sigm(zo0) * tanh_(ncA);
      float ncB = sigm(zf1) * cB + sigm(zi1) * tanh_(zg1);
      float nhB = sigm(zo1) * tanh_(ncB);
      if (t < len) { cA = ncA; hA = nhA; cB = ncB; hB = nhB; }
      unsigned int hp = (unsigned int)f2h(hA) | ((unsigned int)f2h(hB) << 16);
      u64 hv2 = ((u64)(unsigned int)(t + 1) << 32) | (u64)hp;
      const size_t hoff = (size_t)((t + 1) & 1) * BB * 256 + eb * 256 + lblk * 8 + jj;
      st_l2_8(&hlayL[hoff], hv2);   // XCD-local copy (fast path)
      __hip_atomic_store(&hlayG[hoff], hv2, __ATOMIC_RELAXED, __HIP_MEMORY_SCOPE_AGENT);
      if (layer == 0) {
        __hip_atomic_store((unsigned int*)(ws_y + ((size_t)eb * TT + t) * HH + u0), hp,
                           __ATOMIC_RELAXED, __HIP_MEMORY_SCOPE_AGENT);
      } else {
        f32x2 o; o[0] = hA; o[1] = hB;
        *(f32x2*)(out + ((size_t)eb * TT + t) * HH + u0) = o;
      }
    }

    if (it == TT) break;

    // ---- publish flags: syncthreads drains vmcnt (data stores complete first)
    __syncthreads();
    if (tid == 0 && active) {
      st_l2_4(myFlagL, (unsigned int)(t + 1));         // local-L2 flag (both layers)
      if (layer == 0) {
        __hip_atomic_store(flags + (size_t)lblk * FLGSTRIDE, (unsigned int)(it + 1),
                           __ATOMIC_RELAXED, __HIP_MEMORY_SCOPE_AGENT);
      }
    }
    if (layer == 0) {
      const int tn = it + 1;
      if (tn < TT) {
#pragma unroll
        for (int i = 0; i < 8; ++i) {
          int u   = tid + i * 256;
          int row = u >> 6;
          int ce  = (u & 63) * 8;
          int tok = tokens[row * TT + tn];
          const float* src = emb + (size_t)tok * HH + ce;
          f32x4 lo = *(const f32x4*)src;
          f32x4 hi = *(const f32x4*)(src + 4);
          i32x4 w;
          w[0] = pkh2(lo[0], lo[1]); w[1] = pkh2(lo[2], lo[3]);
          w[2] = pkh2(hi[0], hi[1]); w[3] = pkh2(hi[2], hi[3]);
          *(i32x4*)(&Alds[row * ALD + ce]) = w;
        }
      }
    }
  }

  if (layer == 1) {
    const size_t coff = (size_t)BB * TT * HH;
    const size_t hoff = coff + (size_t)BB * HH;
    f32x2 c2; c2[0] = cA; c2[1] = cB;
    f32x2 h2; h2[0] = hA; h2[1] = hB;
    *(f32x2*)(out + coff + (size_t)eb * HH + u0) = c2;
    *(f32x2*)(out + hoff + (size_t)eb * HH + u0) = h2;
  }
}

extern "C" void kernel_launch(void* const* d_in, const int* in_sizes, int n_in,
                              void* d_out, int out_size, void* d_ws, size_t ws_size,
                              hipStream_t stream) {
  (void)in_sizes; (void)n_in; (void)out_size; (void)ws_size;
  const int* tokens  = (const int*)d_in[0];
  const int* lengths = (const int*)d_in[1];
  const float* emb   = (const float*)d_in[2];
  const float* Wx    = (const float*)d_in[3];
  const float* Wh    = (const float*)d_in[4];
  const float* bias  = (const float*)d_in[5];

  // ws layout (~9 MB):
  //   [0, 4K)       fabric flags [32] x 128B
  //   [4K, 4.5K)    ctl [4] x 128B
  //   [4.5K, 12.5K) flagsL [2][32] x 128B (local-L2 flags)
  //   then          htagL, htagG (256K each), ws_y (8M)
  char* w = (char*)d_ws;
  const size_t FB  = (size_t)32 * FLGSTRIDE * 4;      // 4096
  const size_t CT  = 512;
  const size_t FLB = (size_t)64 * FLGSTRIDE * 4;      // 8192
  const size_t HT  = (size_t)2 * 2 * BB * 256 * 8;    // 262144
  unsigned int*   flags  = (unsigned int*)w;
  unsigned int*   ctl    = (unsigned int*)(w + FB);
  unsigned int*   flagsL = (unsigned int*)(w + FB + CT);
  u64*            htagL  = (u64*)(w + FB + CT + FLB);
  u64*            htagG  = (u64*)(w + FB + CT + FLB + HT);
  unsigned short* ws_y   = (unsigned short*)(w + FB + CT + FLB + 2 * HT);

  const int zero_words = (int)((FB + CT + FLB + 2 * HT) / 4);
  hipLaunchKernelGGL(zero_ws_kernel, dim3((zero_words + 255) / 256), dim3(256), 0, stream,
                     (unsigned int*)d_ws, zero_words);
  hipLaunchKernelGGL(lstm_enc_kernel, dim3(GRIDN), dim3(256), 0, stream,
                     tokens, lengths, emb, Wx, Wh, bias, (float*)d_out,
                     ws_y, htagL, htagG, flags, flagsL, ctl);
}

// Round 21
// 1643.581 us; speedup vs baseline: 1.0070x; 1.0070x over previous
//
#include <hip/hip_runtime.h>

#define BB 32
#define TT 256
#define HH 512
#define ALD 1032   // A_lds padded row stride in elements (1024 + 8)
#define ZLD 68     // z_lds padded row stride in floats (64 + 4)
#define FLGSTRIDE 32   // u32s per flag line (128 B)
#define GRIDN 512

typedef float    f32x4 __attribute__((ext_vector_type(4)));
typedef float    f32x2 __attribute__((ext_vector_type(2)));
typedef int      i32x4 __attribute__((ext_vector_type(4)));
typedef _Float16 f16x8 __attribute__((ext_vector_type(8)));
typedef unsigned long long u64;

__device__ __forceinline__ unsigned short f2h(float f) {
  union { _Float16 h; unsigned short u; } v; v.h = (_Float16)f; return v.u;
}
__device__ __forceinline__ int pkh2(float a, float b) {
  return (int)((unsigned int)f2h(a) | ((unsigned int)f2h(b) << 16));
}
__device__ __forceinline__ float sigm(float x) { return 1.f / (1.f + __expf(-x)); }
__device__ __forceinline__ float tanh_(float x) {
  float ax = fabsf(x);
  float e = __expf(-2.f * ax);
  float r = (1.f - e) / (1.f + e);
  return copysignf(r, x);
}
// fabric-coherent pipelined 16B load (sc1: bypasses L1+L2, device scope)
__device__ __forceinline__ void ld_coh16(i32x4& dst, const void* a) {
  asm volatile("global_load_dwordx4 %0, %1, off sc1" : "=v"(dst) : "v"(a) : "memory");
}
// XCD-local pipelined 16B load (sc0: bypasses L1, reads own-XCD shared L2)
__device__ __forceinline__ void ld_l2_16(i32x4& dst, const void* a) {
  asm volatile("global_load_dwordx4 %0, %1, off sc0" : "=v"(dst) : "v"(a) : "memory");
}
// XCD-local 8B store (plain: write-through L1 into own-XCD L2)
__device__ __forceinline__ void st_l2_8(void* a, u64 v) {
  asm volatile("global_store_dwordx2 %0, %1, off" :: "v"(a), "v"(v) : "memory");
}

__global__ void zero_ws_kernel(unsigned int* p, int nwords) {
  int i = blockIdx.x * 256 + threadIdx.x;
  if (i < nwords) p[i] = 0u;
}

// 512 blocks launched; 64 claim roles (L0 on home XCD, L1 on home+1), rest exit.
// h exchanged via own-XCD L2 (sc0/plain, tag-validated) with sticky sc1 fallback.
// RULE (r19/r20 crashes): every inline-asm load batch is drained by s_waitcnt in
// the SAME straight-line region — no in-flight dest registers across control flow.
__global__ __launch_bounds__(256, 1) void lstm_enc_kernel(
    const int* __restrict__ tokens,
    const int* __restrict__ lengths,
    const float* __restrict__ emb,     // [V][512] fp32
    const float* __restrict__ Wx,      // [2][512][2048] fp32
    const float* __restrict__ Wh,      // [2][512][2048] fp32
    const float* __restrict__ bias,    // [2][2048] fp32
    float* __restrict__ out,           // y ++ c ++ h fp32
    unsigned short* __restrict__ ws_y, // [32][256][512] f16 bits
    u64* __restrict__ htagL,           // [2][2][32][256] tagged h (XCD-local copy)
    u64* __restrict__ htagG,           // [2][2][32][256] tagged h (fabric copy)
    unsigned int* __restrict__ flags,  // [32] L0 arrival flags, 128B-strided
    unsigned int* __restrict__ ctl)    // [0]=home|0x100, [32]=ctrA, [64]=ctrB, [96]=claimed
{
  const int tid = threadIdx.x;

  // ---- role claim: L0 roles on home XCD, L1 on home+1; overflow after capped spin
  __shared__ int sRole;
  if (tid == 0) {
    unsigned int xcc;
    asm volatile("s_getreg_b32 %0, hwreg(HW_REG_XCC_ID)" : "=s"(xcc));
    xcc &= 7u;
    if (blockIdx.x == 0) {
      __hip_atomic_store(&ctl[0], 0x100u | xcc, __ATOMIC_RELAXED, __HIP_MEMORY_SCOPE_AGENT);
    }
    unsigned int hw;
    while ((((hw = __hip_atomic_load(&ctl[0], __ATOMIC_RELAXED, __HIP_MEMORY_SCOPE_AGENT))) & 0x100u) == 0u) {
      __builtin_amdgcn_s_sleep(1);
    }
    const unsigned int home0 = hw & 7u, home1 = (home0 + 1u) & 7u;
    int role = -1;
    if (xcc == home0) {
      unsigned int i = __hip_atomic_fetch_add(&ctl[32], 1u, __ATOMIC_RELAXED, __HIP_MEMORY_SCOPE_AGENT);
      if (i < 32u) role = (int)i;
    } else if (xcc == home1) {
      unsigned int i = __hip_atomic_fetch_add(&ctl[64], 1u, __ATOMIC_RELAXED, __HIP_MEMORY_SCOPE_AGENT);
      if (i < 32u) role = 32 + (int)i;
    }
    if (role < 0) {
      unsigned int cl = 0; int spins = 0;
      while ((cl = __hip_atomic_load(&ctl[96], __ATOMIC_RELAXED, __HIP_MEMORY_SCOPE_AGENT)) < 64u
             && spins < 20000) { __builtin_amdgcn_s_sleep(2); ++spins; }
      if (cl < 64u) {
        unsigned int i = __hip_atomic_fetch_add(&ctl[32], 1u, __ATOMIC_RELAXED, __HIP_MEMORY_SCOPE_AGENT);
        if (i < 32u) role = (int)i;
        else {
          unsigned int j = __hip_atomic_fetch_add(&ctl[64], 1u, __ATOMIC_RELAXED, __HIP_MEMORY_SCOPE_AGENT);
          if (j < 32u) role = 32 + (int)j;
        }
      }
    }
    if (role >= 0)
      __hip_atomic_fetch_add(&ctl[96], 1u, __ATOMIC_RELAXED, __HIP_MEMORY_SCOPE_AGENT);
    sRole = role;
  }
  __syncthreads();
  const int role = sRole;
  if (role < 0) return;
  const int layer = role >> 5;
  const int lblk  = role & 31;
  const int wave  = tid >> 6;
  const int lane  = tid & 63;

  __shared__ unsigned short Alds[32 * ALD];
  __shared__ float zlds[32 * ZLD];

  // ---- preload stacked-weight B fragments (K = 1024, N = 16 per wave)
  const int nloc  = lane & 15;
  const int gcol  = wave * HH + lblk * 16 + nloc;
  const int krow0 = (lane >> 4) * 8;
  const float* WxL = Wx + (size_t)layer * HH * 2048;
  const float* WhL = Wh + (size_t)layer * HH * 2048;
  f16x8 breg[32];
#pragma unroll
  for (int s = 0; s < 32; ++s) {
    const float* base = (s < 16)
        ? (WxL + (size_t)(s * 32 + krow0) * 2048 + gcol)
        : (WhL + (size_t)((s - 16) * 32 + krow0) * 2048 + gcol);
    f16x8 v;
    v[0] = (_Float16)base[0 * 2048];
    v[1] = (_Float16)base[1 * 2048];
    v[2] = (_Float16)base[2 * 2048];
    v[3] = (_Float16)base[3 * 2048];
    v[4] = (_Float16)base[4 * 2048];
    v[5] = (_Float16)base[5 * 2048];
    v[6] = (_Float16)base[6 * 2048];
    v[7] = (_Float16)base[7 * 2048];
    breg[s] = v;
  }

  // ---- per-thread elementwise state: one batch, two adjacent units
  const int jj  = tid & 7;
  const int eb  = tid >> 3;
  const int u0  = lblk * 16 + 2 * jj;
  const int len = lengths[eb];
  const float bI0 = bias[layer * 2048 +         u0], bI1 = bias[layer * 2048 +         u0 + 1];
  const float bF0 = bias[layer * 2048 +  512 +  u0], bF1 = bias[layer * 2048 +  512 +  u0 + 1];
  const float bG0 = bias[layer * 2048 + 1024 +  u0], bG1 = bias[layer * 2048 + 1024 +  u0 + 1];
  const float bO0 = bias[layer * 2048 + 1536 +  u0], bO1 = bias[layer * 2048 + 1536 +  u0 + 1];
  float cA = 0.f, hA = 0.f, cB = 0.f, hB = 0.f;

  u64* hlayL = htagL + (size_t)layer * 2 * BB * 256;
  u64* hlayG = htagG + (size_t)layer * 2 * BB * 256;
  unsigned int* pollL0 = flags + (size_t)(tid & 31) * FLGSTRIDE;
  bool useG = false;   // sticky fallback to fabric copy

  // ---- prologue: layer 0 stages x(0) into LDS x-half
  if (layer == 0) {
#pragma unroll
    for (int i = 0; i < 8; ++i) {
      int u   = tid + i * 256;
      int row = u >> 6;
      int ce  = (u & 63) * 8;
      int tok = tokens[row * TT + 0];
      const float* src = emb + (size_t)tok * HH + ce;
      f32x4 lo = *(const f32x4*)src;
      f32x4 hi = *(const f32x4*)(src + 4);
      i32x4 w;
      w[0] = pkh2(lo[0], lo[1]); w[1] = pkh2(lo[2], lo[3]);
      w[2] = pkh2(hi[0], hi[1]); w[3] = pkh2(hi[2], hi[3]);
      *(i32x4*)(&Alds[row * ALD + ce]) = w;
    }
  }

  for (int it = 0;; ++it) {
    const int t = (layer == 0) ? it : (it - 1);
    const bool active = (t >= 0) && (t < TT);

    if (layer == 1 && active) {
      const unsigned int tgt = (unsigned int)(t + 1);
      if (tid < 32) {
        while (__hip_atomic_load(pollL0, __ATOMIC_RELAXED, __HIP_MEMORY_SCOPE_AGENT) < tgt) {
          __builtin_amdgcn_s_sleep(1);
        }
      }
      __syncthreads();
      i32x4 yv[8];
      int yrow[8], yco[8];
#pragma unroll
      for (int k = 0; k < 8; ++k) {
        int g = tid + k * 256;
        yrow[k] = g >> 6;
        yco[k]  = (g & 63) * 8;
        ld_coh16(yv[k], ws_y + ((size_t)yrow[k] * TT + t) * HH + yco[k]);
      }
      asm volatile("s_waitcnt vmcnt(0)" ::: "memory");
      __builtin_amdgcn_sched_barrier(0);
#pragma unroll
      for (int k = 0; k < 8; ++k) {
        *(i32x4*)(&Alds[yrow[k] * ALD + yco[k]]) = yv[k];
      }
    }

    if (active) {
      // ---- tagged h staging: bulk rounds on local L2 copy; sticky sc1 fallback
      const u64* srcL = hlayL + (size_t)(t & 1) * BB * 256;
      const u64* srcG = hlayG + (size_t)(t & 1) * BB * 256;
      const unsigned int exp = (unsigned int)t;
      i32x4 hv[16];
      int rounds = 0;
      bool ok = false;
      while (!ok) {
        if (useG) {
#pragma unroll
          for (int k = 0; k < 16; ++k) ld_coh16(hv[k], srcG + 2 * (tid + k * 256));
        } else {
#pragma unroll
          for (int k = 0; k < 16; ++k) ld_l2_16(hv[k], srcL + 2 * (tid + k * 256));
        }
        asm volatile("s_waitcnt vmcnt(0)" ::: "memory");
        __builtin_amdgcn_sched_barrier(0);
        ok = true;
#pragma unroll
        for (int k = 0; k < 16; ++k) {
          if ((unsigned int)hv[k][1] != exp) ok = false;
          if ((unsigned int)hv[k][3] != exp) ok = false;
        }
        if (!ok && ++rounds > 48) useG = true;
      }
#pragma unroll
      for (int k = 0; k < 16; ++k) {
        int g   = tid + k * 256;
        int row = g >> 7;
        int e   = 4 * (g & 127);
        u64 d = (u64)(unsigned int)hv[k][0] | ((u64)(unsigned int)hv[k][2] << 32);
        *(u64*)(&Alds[row * ALD + 512 + e]) = d;
      }
    }
    __syncthreads();

    if (active) {
      f32x4 acc0 = {0.f, 0.f, 0.f, 0.f};
      f32x4 acc1 = {0.f, 0.f, 0.f, 0.f};
      const _Float16* a0p = (const _Float16*)&Alds[nloc * ALD + krow0];
      const _Float16* a1p = a0p + 16 * ALD;
#pragma unroll
      for (int s = 0; s < 32; ++s) {
        f16x8 a0 = *(const f16x8*)(a0p + s * 32);
        f16x8 a1 = *(const f16x8*)(a1p + s * 32);
        acc0 = __builtin_amdgcn_mfma_f32_16x16x32_f16(a0, breg[s], acc0, 0, 0, 0);
        acc1 = __builtin_amdgcn_mfma_f32_16x16x32_f16(a1, breg[s], acc1, 0, 0, 0);
      }
      const int zc = wave * 16 + nloc;
      const int zr = (lane >> 4) * 4;
#pragma unroll
      for (int r = 0; r < 4; ++r) {
        zlds[(zr + r) * ZLD + zc]        = acc0[r];
        zlds[(16 + zr + r) * ZLD + zc]   = acc1[r];
      }
    }
    __syncthreads();

    if (active) {
      float zi0 = zlds[eb * ZLD +      2 * jj] + bI0, zi1 = zlds[eb * ZLD +      2 * jj + 1] + bI1;
      float zf0 = zlds[eb * ZLD + 16 + 2 * jj] + bF0, zf1 = zlds[eb * ZLD + 16 + 2 * jj + 1] + bF1;
      float zg0 = zlds[eb * ZLD + 32 + 2 * jj] + bG0, zg1 = zlds[eb * ZLD + 32 + 2 * jj + 1] + bG1;
      float zo0 = zlds[eb * ZLD + 48 + 2 * jj] + bO0, zo1 = zlds[eb * ZLD + 48 + 2 * jj + 1] + bO1;
      float ncA = sigm(zf0) * cA + sigm(zi0) * tanh_(zg0);
      float nhA = sigm(zo0) * tanh_(ncA);
      float ncB = sigm(zf1) * cB + sigm(zi1) * tanh_(zg1);
      float nhB = sigm(zo1) * tanh_(ncB);
      if (t < len) { cA = ncA; hA = nhA; cB = ncB; hB = nhB; }
      unsigned int hp = (unsigned int)f2h(hA) | ((unsigned int)f2h(hB) << 16);
      u64 hv2 = ((u64)(unsigned int)(t + 1) << 32) | (u64)hp;
      const size_t hoff = (size_t)((t + 1) & 1) * BB * 256 + eb * 256 + lblk * 8 + jj;
      st_l2_8(&hlayL[hoff], hv2);   // XCD-local copy (fast path)
      __hip_atomic_store(&hlayG[hoff], hv2, __ATOMIC_RELAXED, __HIP_MEMORY_SCOPE_AGENT);
      if (layer == 0) {
        __hip_atomic_store((unsigned int*)(ws_y + ((size_t)eb * TT + t) * HH + u0), hp,
                           __ATOMIC_RELAXED, __HIP_MEMORY_SCOPE_AGENT);
      } else {
        f32x2 o; o[0] = hA; o[1] = hB;
        *(f32x2*)(out + ((size_t)eb * TT + t) * HH + u0) = o;
      }
    }

    if (it == TT) break;

    if (layer == 0) {
      // drain ws_y stores, then publish per-step flag (guards L1's ws_y reads)
      __syncthreads();
      if (tid == 0 && active) {
        __hip_atomic_store(flags + (size_t)lblk * FLGSTRIDE, (unsigned int)(it + 1),
                           __ATOMIC_RELAXED, __HIP_MEMORY_SCOPE_AGENT);
      }
      // prefetch next x (emb gather) into LDS x-half (distinct from zlds/h-half)
      const int tn = it + 1;
      if (tn < TT) {
#pragma unroll
        for (int i = 0; i < 8; ++i) {
          int u   = tid + i * 256;
          int row = u >> 6;
          int ce  = (u & 63) * 8;
          int tok = tokens[row * TT + tn];
          const float* src = emb + (size_t)tok * HH + ce;
          f32x4 lo = *(const f32x4*)src;
          f32x4 hi = *(const f32x4*)(src + 4);
          i32x4 w;
          w[0] = pkh2(lo[0], lo[1]); w[1] = pkh2(lo[2], lo[3]);
          w[2] = pkh2(hi[0], hi[1]); w[3] = pkh2(hi[2], hi[3]);
          *(i32x4*)(&Alds[row * ALD + ce]) = w;
        }
      }
    }
  }

  if (layer == 1) {
    const size_t coff = (size_t)BB * TT * HH;
    const size_t hoff = coff + (size_t)BB * HH;
    f32x2 c2; c2[0] = cA; c2[1] = cB;
    f32x2 h2; h2[0] = hA; h2[1] = hB;
    *(f32x2*)(out + coff + (size_t)eb * HH + u0) = c2;
    *(f32x2*)(out + hoff + (size_t)eb * HH + u0) = h2;
  }
}

extern "C" void kernel_launch(void* const* d_in, const int* in_sizes, int n_in,
                              void* d_out, int out_size, void* d_ws, size_t ws_size,
                              hipStream_t stream) {
  (void)in_sizes; (void)n_in; (void)out_size; (void)ws_size;
  const int* tokens  = (const int*)d_in[0];
  const int* lengths = (const int*)d_in[1];
  const float* emb   = (const float*)d_in[2];
  const float* Wx    = (const float*)d_in[3];
  const float* Wh    = (const float*)d_in[4];
  const float* bias  = (const float*)d_in[5];

  // ws layout (~8.9 MB):
  //   [0, 4K)         flags [32] x 128B
  //   [4K, 4.5K)      ctl   [4] x 128B
  //   [4.5K, +256K)   htagL [2][2][32][256] u64
  //   [+256K)         htagG (same shape)
  //   then            ws_y  [32][256][512] u16
  char* w = (char*)d_ws;
  const size_t FB = (size_t)32 * FLGSTRIDE * 4;       // 4096
  const size_t CT = 512;
  const size_t HT = (size_t)2 * 2 * BB * 256 * 8;     // 262144
  unsigned int*   flags = (unsigned int*)w;
  unsigned int*   ctl   = (unsigned int*)(w + FB);
  u64*            htagL = (u64*)(w + FB + CT);
  u64*            htagG = (u64*)(w + FB + CT + HT);
  unsigned short* ws_y  = (unsigned short*)(w + FB + CT + 2 * HT);

  const int zero_words = (int)((FB + CT + 2 * HT) / 4);
  hipLaunchKernelGGL(zero_ws_kernel, dim3((zero_words + 255) / 256), dim3(256), 0, stream,
                     (unsigned int*)d_ws, zero_words);
  hipLaunchKernelGGL(lstm_enc_kernel, dim3(GRIDN), dim3(256), 0, stream,
                     tokens, lengths, emb, Wx, Wh, bias, (float*)d_out,
                     ws_y, htagL, htagG, flags, ctl);
}